// Round 8
// baseline (146.172 us; speedup 1.0000x reference)
//
#include <hip/hip_runtime.h>
#include <stdint.h>

// Problem constants (B=2048, N=16, T=1024)
#define T_STEPS 1024
#define NWORDS  256          // u64 mask words per batch (4 timesteps per word)
#define NB      8            // batches per scan block
#define SCAN_BLOCK (NB * 16) // 128 threads: 8 batches x 16 output neurons

typedef float f32x4 __attribute__((ext_vector_type(4)));

// ---------------------------------------------------------------------------
// Kernel 1: spikes -> 16-bit masks, 4 timesteps per u64. HBM-bound 128 MiB.
// ---------------------------------------------------------------------------
__global__ __launch_bounds__(256) void k_maskify(const float* __restrict__ spike,
                                                 unsigned long long* __restrict__ masks) {
    const int b  = blockIdx.x;
    const int tc = threadIdx.x;
    const float4* sp = reinterpret_cast<const float4*>(spike) + (size_t)b * (16 * NWORDS);
    unsigned int m0 = 0, m1 = 0, m2 = 0, m3 = 0;
#pragma unroll
    for (int i = 0; i < 16; ++i) {
        float4 v = sp[i * NWORDS + tc];
        m0 |= (v.x >= 0.5f) ? (1u << i) : 0u;
        m1 |= (v.y >= 0.5f) ? (1u << i) : 0u;
        m2 |= (v.z >= 0.5f) ? (1u << i) : 0u;
        m3 |= (v.w >= 0.5f) ? (1u << i) : 0u;
    }
    masks[(size_t)b * NWORDS + tc] =
        (unsigned long long)m0 | ((unsigned long long)m1 << 16) |
        ((unsigned long long)m2 << 32) | ((unsigned long long)m3 << 48);
}

// ---------------------------------------------------------------------------
// Kernel 2: build the f64 byte table in GLOBAL memory (64 KiB, L1/L2-hot).
// tab[s*4096 + byte*16 + o] = (lo-nibble ordered sum) + (hi-nibble ordered sum)
// == z_{2s} + z_{2s+1} with the EXACT association tree of the absmax-0 rounds.
// ---------------------------------------------------------------------------
__global__ __launch_bounds__(128) void k_ztab(const float* __restrict__ W,
                                              double* __restrict__ tab) {
    const int tid = threadIdx.x;
    const int o   = tid & 15;
    double w[16];
#pragma unroll
    for (int j = 0; j < 16; ++j) w[j] = (double)W[o * 16 + j];
    for (int k = 0; k < 64; ++k) {
        const int e    = tid + k * 128;
        const int byte = (e >> 4) & 255;
        const int s    = e >> 12;
        double slo = 0.0, shi = 0.0;
#pragma unroll
        for (int j = 0; j < 4; ++j) slo += (byte & (1 << j))  ? w[8 * s + j]     : 0.0;
#pragma unroll
        for (int j = 0; j < 4; ++j) shi += (byte & (16 << j)) ? w[8 * s + 4 + j] : 0.0;
        tab[s * 4096 + byte * 16 + o] = slo + shi;
    }
}

// ---------------------------------------------------------------------------
// Kernel 3: CUBA LIF scan — asm-pipelined, ALL-GLOBAL (no LDS, no barriers,
// single in-order vmcnt ledger owned by hand).
// Per word tg: [1 mask load (tg+4)] [s_waitcnt vmcnt(12)] [8 table loads tg+2]
//             [f64 chain for word tg] [1 dwordx4 store].
// Steady-state newest-12 = {Lm,S,T(tg+1)x8,Lm,S} -> the wait forces exactly
// T(tg) + mask(tg+2), leaving 2 table-words + 2 masks + 2 stores in flight.
// Register sets rotate with period-3 unrolling (no copies of in-flight asm
// destinations). Output via exp2f(16 + k*log2(cosh 1)) — abs err <= ~31,
// threshold is 27361; spike decisions use identical f64 math to the
// absmax-0 rounds.
// ---------------------------------------------------------------------------
__global__ __launch_bounds__(SCAN_BLOCK, 1) void k_scan(const double* __restrict__ tab,
                                                        const unsigned long long* __restrict__ masks,
                                                        float* __restrict__ out) {
    const int tid = threadIdx.x;
    const int bb  = tid >> 4;
    const int o   = tid & 15;
    const int b   = blockIdx.x * NB + bb;

    const uint64_t tb     = (uint64_t)tab;
    const uint64_t mb     = (uint64_t)masks;
    const uint64_t ob_out = (uint64_t)out;
    const uint32_t ob0    = (uint32_t)(o * 8);
    const uint32_t ob1    = ob0 + 32768u;
    const uint32_t vb_m   = (uint32_t)(b * (NWORDS * 8));
    const uint32_t vb_out = (uint32_t)(b * (T_STEPS * 4));
    const int grp_sh      = tid & 48;
    const bool writer     = (o == 0);

    double c = 0.0, v = 0.0;

    // Rotating register sets (period 3): table words + mask words.
    double T0_0, T0_1, T0_2, T0_3, T0_4, T0_5, T0_6, T0_7;
    double T1_0, T1_1, T1_2, T1_3, T1_4, T1_5, T1_6, T1_7;
    double T2_0, T2_1, T2_2, T2_3, T2_4, T2_5, T2_6, T2_7;
    unsigned long long M0, M1, M2, q0, q1;

#define GLT(DST, VOFF) \
    asm volatile("global_load_dwordx2 %0, %1, %2" : "=v"(DST) : "v"(VOFF), "s"(tb) : "memory")
#define GLM(DST, IDX) do { int _mi = (IDX); if (_mi > 255) _mi = 255;                 \
    const uint32_t _vo = vb_m + ((uint32_t)_mi << 3);                                 \
    asm volatile("global_load_dwordx2 %0, %1, %2" : "=v"(DST) : "v"(_vo), "s"(mb) : "memory"); } while (0)
#define WAITV(N) asm volatile("s_waitcnt vmcnt(" #N ")" ::: "memory")
#define SBAR __builtin_amdgcn_sched_barrier(0)

#define TISSUE(P, MW) do {                                                            \
    const uint32_t _lo = (uint32_t)(MW), _hi = (uint32_t)((MW) >> 32);                \
    uint32_t _a;                                                                      \
    _a = ob0 + ((_lo & 255u) << 7);          GLT(P##_0, _a);                          \
    _a = ob1 + (((_lo >> 8) & 255u) << 7);   GLT(P##_1, _a);                          \
    _a = ob0 + (((_lo >> 16) & 255u) << 7);  GLT(P##_2, _a);                          \
    _a = ob1 + ((_lo >> 24) << 7);           GLT(P##_3, _a);                          \
    _a = ob0 + ((_hi & 255u) << 7);          GLT(P##_4, _a);                          \
    _a = ob1 + (((_hi >> 8) & 255u) << 7);   GLT(P##_5, _a);                          \
    _a = ob0 + (((_hi >> 16) & 255u) << 7);  GLT(P##_6, _a);                          \
    _a = ob1 + ((_hi >> 24) << 7);           GLT(P##_7, _a);                          \
} while (0)

    // One recurrence step; numerics identical to the absmax-0 rounds:
    // z = (z01)+(z23) via table halves, fma(c,0.75,z), fma(v,0.97,c).
#define ZSTEP(ZL, ZH, OWEL) do {                                                      \
    const double _z = (ZL) + (ZH);                                                    \
    c = fma(c, 0.75, _z);                                                             \
    v = fma(v, 0.97, c);                                                              \
    const bool _s = (v >= 1.25);                                                      \
    const unsigned long long _bal = __ballot(_s);                                     \
    v = _s ? 0.0 : v;                                                                 \
    const uint32_t _k = __popc((uint32_t)(_bal >> grp_sh) & 0xFFFFu);                 \
    OWEL = exp2f(fmaf((float)_k, 0.62581400f, 16.0f));                                \
} while (0)

#define COMPUTE(P, W) do {                                                            \
    f32x4 _ow;                                                                        \
    ZSTEP(P##_0, P##_1, _ow.x);                                                       \
    ZSTEP(P##_2, P##_3, _ow.y);                                                       \
    ZSTEP(P##_4, P##_5, _ow.z);                                                       \
    ZSTEP(P##_6, P##_7, _ow.w);                                                       \
    if (writer) {                                                                     \
        const uint32_t _vo = vb_out + ((uint32_t)(W) << 4);                           \
        asm volatile("global_store_dwordx4 %0, %1, %2"                                \
                     :: "v"(_vo), "v"(_ow), "s"(ob_out) : "memory");                  \
    }                                                                                 \
} while (0)

#define BODY(W, TU, TI, MU, MI) do {                                                  \
    GLM(MI, (W) + 4);                                                                 \
    WAITV(12); SBAR;                                                                  \
    TISSUE(TI, MU); SBAR;                                                             \
    COMPUTE(TU, W);                                                                   \
} while (0)

    // Ledger starts clean: drain anything the prologue address math caused.
    asm volatile("s_waitcnt vmcnt(0) lgkmcnt(0)" ::: "memory");

    // Prologue: masks 0..3 in flight; tables for words 0,1 in flight.
    GLM(q0, 0); GLM(q1, 1); GLM(M2, 2); GLM(M0, 3);
    WAITV(2); SBAR;                 // q0,q1 ready; M2,M0 outstanding
    TISSUE(T0, q0);
    TISSUE(T1, q1); SBAR;           // outstanding: 2 masks + 16 table

    // Peeled word 0: force T0 + mask[2]; issue T(2); compute word 0.
    GLM(M1, 4);
    WAITV(9); SBAR;
    TISSUE(T2, M2); SBAR;
    COMPUTE(T0, 0);

    // Peeled word 1: force T1 + mask[3]; issue T(3); compute word 1.
    GLM(M2, 5);
    WAITV(11); SBAR;
    TISSUE(T0, M0); SBAR;
    COMPUTE(T1, 1);

    // Steady state: words 2..253, unrolled x3 (register-set rotation period).
    for (int w = 2; w < 254; w += 3) {
        BODY(w,     T2, T1, M1, M0);
        BODY(w + 1, T0, T2, M2, M1);
        BODY(w + 2, T1, T0, M0, M2);
    }

    // Epilogue: words 254 (set 2) and 255 (set 0).
    WAITV(11); SBAR;
    COMPUTE(T2, 254);
    WAITV(2); SBAR;
    COMPUTE(T0, 255);

#undef GLT
#undef GLM
#undef WAITV
#undef SBAR
#undef TISSUE
#undef ZSTEP
#undef COMPUTE
#undef BODY
}

// ---------------------------------------------------------------------------
// Fallback (only if d_ws is too small — never observed): self-contained
// R1-style scan, correctness over speed.
// ---------------------------------------------------------------------------
__global__ __launch_bounds__(SCAN_BLOCK) void k_scan_fb(const float* __restrict__ W,
                                                        const float* __restrict__ spike,
                                                        float* __restrict__ out) {
    __shared__ double ztab[4][16][16];
    __shared__ unsigned long long mlds[NB][NWORDS];
    __shared__ float outtab[17];
    const int tid = threadIdx.x, bb = tid >> 4, o = tid & 15;
    for (int e = tid; e < 4 * 16 * 16; e += SCAN_BLOCK) {
        const int oo = e & 15, idx = (e >> 4) & 15, seg = e >> 8;
        double s = 0.0;
#pragma unroll
        for (int j = 0; j < 4; ++j)
            if (idx & (1 << j)) s += (double)W[oo * 16 + seg * 4 + j];
        ztab[seg][idx][oo] = s;
    }
    if (tid < 17) {
        const double ln2 = 0.69314718055994530941723212145818;
        const double l2c1 = log(2.0 * cosh(1.0));
        outtab[tid] = (float)exp((16.0 - (double)tid) * ln2 + (double)tid * l2c1);
    }
    {
        const int part = tid & 15;
        const float4* spb = reinterpret_cast<const float4*>(spike) +
                            (size_t)(blockIdx.x * NB + bb) * (16 * NWORDS);
        for (int w = 0; w < 16; ++w) {
            const int tc = part * 16 + w;
            unsigned int m0 = 0, m1 = 0, m2 = 0, m3 = 0;
#pragma unroll
            for (int i = 0; i < 16; ++i) {
                float4 v = spb[i * NWORDS + tc];
                m0 |= (v.x >= 0.5f) ? (1u << i) : 0u;
                m1 |= (v.y >= 0.5f) ? (1u << i) : 0u;
                m2 |= (v.z >= 0.5f) ? (1u << i) : 0u;
                m3 |= (v.w >= 0.5f) ? (1u << i) : 0u;
            }
            mlds[bb][tc] = (unsigned long long)m0 | ((unsigned long long)m1 << 16) |
                           ((unsigned long long)m2 << 32) | ((unsigned long long)m3 << 48);
        }
    }
    __syncthreads();
    double c = 0.0, v = 0.0;
    const int b = blockIdx.x * NB + bb;
    float* outp = out + (size_t)b * T_STEPS;
    const int grp_sh = tid & 48;
    const bool writer = (o == 0);
    for (int tg = 0; tg < NWORDS; ++tg) {
        const unsigned long long mw = mlds[bb][tg];
#pragma unroll
        for (int j = 0; j < 4; ++j) {
            const unsigned int m = (unsigned int)(mw >> (16 * j)) & 0xFFFFu;
            const double z = (ztab[0][m & 15][o] + ztab[1][(m >> 4) & 15][o]) +
                             (ztab[2][(m >> 8) & 15][o] + ztab[3][(m >> 12) & 15][o]);
            c = fma(c, 0.75, z);
            v = fma(v, 0.97, c);
            const bool s = (v >= 1.25);
            const unsigned long long bal = __ballot(s);
            v = s ? 0.0 : v;
            if (writer) outp[tg * 4 + j] = outtab[(int)__popcll((bal >> grp_sh) & 0xFFFFull)];
        }
    }
}

extern "C" void kernel_launch(void* const* d_in, const int* in_sizes, int n_in,
                              void* d_out, int out_size, void* d_ws, size_t ws_size,
                              hipStream_t stream) {
    const float* spike = (const float*)d_in[0];
    const float* W     = (const float*)d_in[1];
    float* out         = (float*)d_out;

    const int B = in_sizes[0] / (16 * T_STEPS);  // 2048

    const size_t mask_bytes = (size_t)B * NWORDS * sizeof(unsigned long long);  // 4 MiB
    const size_t tab_bytes  = 2 * 256 * 16 * sizeof(double);                    // 64 KiB

    if (ws_size >= mask_bytes + tab_bytes) {
        unsigned long long* masks = (unsigned long long*)d_ws;
        double* tab = (double*)((char*)d_ws + mask_bytes);
        k_maskify<<<B, 256, 0, stream>>>(spike, masks);
        k_ztab<<<1, 128, 0, stream>>>(W, tab);
        k_scan<<<B / NB, SCAN_BLOCK, 0, stream>>>(tab, masks, out);
    } else {
        k_scan_fb<<<B / NB, SCAN_BLOCK, 0, stream>>>(W, spike, out);
    }
}

// Round 9
// 93.264 us; speedup vs baseline: 1.5673x; 1.5673x over previous
//
#include <hip/hip_runtime.h>
#include <stdint.h>

// Problem constants (B=2048, N=16, T=1024)
#define T_STEPS 1024
#define NWORDS  256          // u64 mask words per batch (4 timesteps per word)
#define NB      8            // batches per scan block
#define SCAN_BLOCK (NB * 16) // 128 threads: 8 batches x 16 output neurons

typedef float f32x4 __attribute__((ext_vector_type(4)));

// ---------------------------------------------------------------------------
// Kernel 1: blocks 0..B-1: spikes -> 16-bit masks (HBM-bound 128 MiB read).
// Block B: build the 64 KiB f64 byte table in global memory — runs CONCURRENT
// with the mask blocks (R8's separate 1-block k_ztab serialized the graph and
// cost ~55 us because w[8*s+j] had runtime s -> scratch; here k is fully
// unrolled so s = k>>4 is compile-time and w[] stays in registers).
// tab[s*4096 + byte*16 + o] = (lo-nibble ordered sum) + (hi-nibble ordered sum)
// == z_{2s} + z_{2s+1} with the EXACT association tree of the absmax-0 rounds.
// ---------------------------------------------------------------------------
__global__ __launch_bounds__(256) void k_maskify(const float* __restrict__ spike,
                                                 unsigned long long* __restrict__ masks,
                                                 const float* __restrict__ W,
                                                 double* __restrict__ tab,
                                                 int B) {
    const int b  = blockIdx.x;
    const int tc = threadIdx.x;
    if (b < B) {
        const float4* sp = reinterpret_cast<const float4*>(spike) + (size_t)b * (16 * NWORDS);
        unsigned int m0 = 0, m1 = 0, m2 = 0, m3 = 0;
#pragma unroll
        for (int i = 0; i < 16; ++i) {
            float4 v = sp[i * NWORDS + tc];
            m0 |= (v.x >= 0.5f) ? (1u << i) : 0u;
            m1 |= (v.y >= 0.5f) ? (1u << i) : 0u;
            m2 |= (v.z >= 0.5f) ? (1u << i) : 0u;
            m3 |= (v.w >= 0.5f) ? (1u << i) : 0u;
        }
        masks[(size_t)b * NWORDS + tc] =
            (unsigned long long)m0 | ((unsigned long long)m1 << 16) |
            ((unsigned long long)m2 << 32) | ((unsigned long long)m3 << 48);
    } else {
        // Table block: 256 threads x 32 entries = 8192 = 2*256*16.
        const int o = tc & 15;
        double w[16];
#pragma unroll
        for (int j = 0; j < 16; ++j) w[j] = (double)W[o * 16 + j];
#pragma unroll
        for (int k = 0; k < 32; ++k) {                 // fully unrolled
            const int e    = tc + k * 256;
            const int byte = (e >> 4) & 255;
            const int s    = k >> 4;                   // COMPILE-TIME constant
            double slo = 0.0, shi = 0.0;
#pragma unroll
            for (int j = 0; j < 4; ++j) slo += (byte & (1 << j))  ? w[8 * s + j]     : 0.0;
#pragma unroll
            for (int j = 0; j < 4; ++j) shi += (byte & (16 << j)) ? w[8 * s + 4 + j] : 0.0;
            tab[s * 4096 + byte * 16 + o] = slo + shi; // = z_{2s} + z_{2s+1}
        }
    }
}

// ---------------------------------------------------------------------------
// Kernel 2: CUBA LIF scan — asm-pipelined, ALL-GLOBAL (no LDS, no barriers,
// single in-order vmcnt ledger owned by hand). BYTE-IDENTICAL to R8's k_scan.
// Per word tg: [1 mask load (tg+4)] [s_waitcnt vmcnt(12)] [8 table loads tg+2]
//             [f64 chain for word tg] [1 dwordx4 store].
// Steady-state newest-12 = {Lm,S,T(tg+1)x8,Lm,S} -> the wait forces exactly
// T(tg) + mask(tg+2), leaving 2 table-words + 2 masks + 2 stores in flight.
// ---------------------------------------------------------------------------
__global__ __launch_bounds__(SCAN_BLOCK, 1) void k_scan(const double* __restrict__ tab,
                                                        const unsigned long long* __restrict__ masks,
                                                        float* __restrict__ out) {
    const int tid = threadIdx.x;
    const int bb  = tid >> 4;
    const int o   = tid & 15;
    const int b   = blockIdx.x * NB + bb;

    const uint64_t tb     = (uint64_t)tab;
    const uint64_t mb     = (uint64_t)masks;
    const uint64_t ob_out = (uint64_t)out;
    const uint32_t ob0    = (uint32_t)(o * 8);
    const uint32_t ob1    = ob0 + 32768u;
    const uint32_t vb_m   = (uint32_t)(b * (NWORDS * 8));
    const uint32_t vb_out = (uint32_t)(b * (T_STEPS * 4));
    const int grp_sh      = tid & 48;
    const bool writer     = (o == 0);

    double c = 0.0, v = 0.0;

    // Rotating register sets (period 3): table words + mask words.
    double T0_0, T0_1, T0_2, T0_3, T0_4, T0_5, T0_6, T0_7;
    double T1_0, T1_1, T1_2, T1_3, T1_4, T1_5, T1_6, T1_7;
    double T2_0, T2_1, T2_2, T2_3, T2_4, T2_5, T2_6, T2_7;
    unsigned long long M0, M1, M2, q0, q1;

#define GLT(DST, VOFF) \
    asm volatile("global_load_dwordx2 %0, %1, %2" : "=v"(DST) : "v"(VOFF), "s"(tb) : "memory")
#define GLM(DST, IDX) do { int _mi = (IDX); if (_mi > 255) _mi = 255;                 \
    const uint32_t _vo = vb_m + ((uint32_t)_mi << 3);                                 \
    asm volatile("global_load_dwordx2 %0, %1, %2" : "=v"(DST) : "v"(_vo), "s"(mb) : "memory"); } while (0)
#define WAITV(N) asm volatile("s_waitcnt vmcnt(" #N ")" ::: "memory")
#define SBAR __builtin_amdgcn_sched_barrier(0)

#define TISSUE(P, MW) do {                                                            \
    const uint32_t _lo = (uint32_t)(MW), _hi = (uint32_t)((MW) >> 32);                \
    uint32_t _a;                                                                      \
    _a = ob0 + ((_lo & 255u) << 7);          GLT(P##_0, _a);                          \
    _a = ob1 + (((_lo >> 8) & 255u) << 7);   GLT(P##_1, _a);                          \
    _a = ob0 + (((_lo >> 16) & 255u) << 7);  GLT(P##_2, _a);                          \
    _a = ob1 + ((_lo >> 24) << 7);           GLT(P##_3, _a);                          \
    _a = ob0 + ((_hi & 255u) << 7);          GLT(P##_4, _a);                          \
    _a = ob1 + (((_hi >> 8) & 255u) << 7);   GLT(P##_5, _a);                          \
    _a = ob0 + (((_hi >> 16) & 255u) << 7);  GLT(P##_6, _a);                          \
    _a = ob1 + ((_hi >> 24) << 7);           GLT(P##_7, _a);                          \
} while (0)

    // One recurrence step; numerics identical to the absmax-0 rounds:
    // z = (z01)+(z23) via table halves, fma(c,0.75,z), fma(v,0.97,c).
#define ZSTEP(ZL, ZH, OWEL) do {                                                      \
    const double _z = (ZL) + (ZH);                                                    \
    c = fma(c, 0.75, _z);                                                             \
    v = fma(v, 0.97, c);                                                              \
    const bool _s = (v >= 1.25);                                                      \
    const unsigned long long _bal = __ballot(_s);                                     \
    v = _s ? 0.0 : v;                                                                 \
    const uint32_t _k = __popc((uint32_t)(_bal >> grp_sh) & 0xFFFFu);                 \
    OWEL = exp2f(fmaf((float)_k, 0.62581400f, 16.0f));                                \
} while (0)

#define COMPUTE(P, W) do {                                                            \
    f32x4 _ow;                                                                        \
    ZSTEP(P##_0, P##_1, _ow.x);                                                       \
    ZSTEP(P##_2, P##_3, _ow.y);                                                       \
    ZSTEP(P##_4, P##_5, _ow.z);                                                       \
    ZSTEP(P##_6, P##_7, _ow.w);                                                       \
    if (writer) {                                                                     \
        const uint32_t _vo = vb_out + ((uint32_t)(W) << 4);                           \
        asm volatile("global_store_dwordx4 %0, %1, %2"                                \
                     :: "v"(_vo), "v"(_ow), "s"(ob_out) : "memory");                  \
    }                                                                                 \
} while (0)

#define BODY(W, TU, TI, MU, MI) do {                                                  \
    GLM(MI, (W) + 4);                                                                 \
    WAITV(12); SBAR;                                                                  \
    TISSUE(TI, MU); SBAR;                                                             \
    COMPUTE(TU, W);                                                                   \
} while (0)

    // Ledger starts clean: drain anything the prologue address math caused.
    asm volatile("s_waitcnt vmcnt(0) lgkmcnt(0)" ::: "memory");

    // Prologue: masks 0..3 in flight; tables for words 0,1 in flight.
    GLM(q0, 0); GLM(q1, 1); GLM(M2, 2); GLM(M0, 3);
    WAITV(2); SBAR;                 // q0,q1 ready; M2,M0 outstanding
    TISSUE(T0, q0);
    TISSUE(T1, q1); SBAR;           // outstanding: 2 masks + 16 table

    // Peeled word 0: force T0 + mask[2]; issue T(2); compute word 0.
    GLM(M1, 4);
    WAITV(9); SBAR;
    TISSUE(T2, M2); SBAR;
    COMPUTE(T0, 0);

    // Peeled word 1: force T1 + mask[3]; issue T(3); compute word 1.
    GLM(M2, 5);
    WAITV(11); SBAR;
    TISSUE(T0, M0); SBAR;
    COMPUTE(T1, 1);

    // Steady state: words 2..253, unrolled x3 (register-set rotation period).
    for (int w = 2; w < 254; w += 3) {
        BODY(w,     T2, T1, M1, M0);
        BODY(w + 1, T0, T2, M2, M1);
        BODY(w + 2, T1, T0, M0, M2);
    }

    // Epilogue: words 254 (set 2) and 255 (set 0).
    WAITV(11); SBAR;
    COMPUTE(T2, 254);
    WAITV(2); SBAR;
    COMPUTE(T0, 255);

#undef GLT
#undef GLM
#undef WAITV
#undef SBAR
#undef TISSUE
#undef ZSTEP
#undef COMPUTE
#undef BODY
}

// ---------------------------------------------------------------------------
// Fallback (only if d_ws is too small — never observed): self-contained
// R1-style scan, correctness over speed.
// ---------------------------------------------------------------------------
__global__ __launch_bounds__(SCAN_BLOCK) void k_scan_fb(const float* __restrict__ W,
                                                        const float* __restrict__ spike,
                                                        float* __restrict__ out) {
    __shared__ double ztab[4][16][16];
    __shared__ unsigned long long mlds[NB][NWORDS];
    __shared__ float outtab[17];
    const int tid = threadIdx.x, bb = tid >> 4, o = tid & 15;
    for (int e = tid; e < 4 * 16 * 16; e += SCAN_BLOCK) {
        const int oo = e & 15, idx = (e >> 4) & 15, seg = e >> 8;
        double s = 0.0;
#pragma unroll
        for (int j = 0; j < 4; ++j)
            if (idx & (1 << j)) s += (double)W[oo * 16 + seg * 4 + j];
        ztab[seg][idx][oo] = s;
    }
    if (tid < 17) {
        const double ln2 = 0.69314718055994530941723212145818;
        const double l2c1 = log(2.0 * cosh(1.0));
        outtab[tid] = (float)exp((16.0 - (double)tid) * ln2 + (double)tid * l2c1);
    }
    {
        const int part = tid & 15;
        const float4* spb = reinterpret_cast<const float4*>(spike) +
                            (size_t)(blockIdx.x * NB + bb) * (16 * NWORDS);
        for (int w = 0; w < 16; ++w) {
            const int tc = part * 16 + w;
            unsigned int m0 = 0, m1 = 0, m2 = 0, m3 = 0;
#pragma unroll
            for (int i = 0; i < 16; ++i) {
                float4 v = spb[i * NWORDS + tc];
                m0 |= (v.x >= 0.5f) ? (1u << i) : 0u;
                m1 |= (v.y >= 0.5f) ? (1u << i) : 0u;
                m2 |= (v.z >= 0.5f) ? (1u << i) : 0u;
                m3 |= (v.w >= 0.5f) ? (1u << i) : 0u;
            }
            mlds[bb][tc] = (unsigned long long)m0 | ((unsigned long long)m1 << 16) |
                           ((unsigned long long)m2 << 32) | ((unsigned long long)m3 << 48);
        }
    }
    __syncthreads();
    double c = 0.0, v = 0.0;
    const int b = blockIdx.x * NB + bb;
    float* outp = out + (size_t)b * T_STEPS;
    const int grp_sh = tid & 48;
    const bool writer = (o == 0);
    for (int tg = 0; tg < NWORDS; ++tg) {
        const unsigned long long mw = mlds[bb][tg];
#pragma unroll
        for (int j = 0; j < 4; ++j) {
            const unsigned int m = (unsigned int)(mw >> (16 * j)) & 0xFFFFu;
            const double z = (ztab[0][m & 15][o] + ztab[1][(m >> 4) & 15][o]) +
                             (ztab[2][(m >> 8) & 15][o] + ztab[3][(m >> 12) & 15][o]);
            c = fma(c, 0.75, z);
            v = fma(v, 0.97, c);
            const bool s = (v >= 1.25);
            const unsigned long long bal = __ballot(s);
            v = s ? 0.0 : v;
            if (writer) outp[tg * 4 + j] = outtab[(int)__popcll((bal >> grp_sh) & 0xFFFFull)];
        }
    }
}

extern "C" void kernel_launch(void* const* d_in, const int* in_sizes, int n_in,
                              void* d_out, int out_size, void* d_ws, size_t ws_size,
                              hipStream_t stream) {
    const float* spike = (const float*)d_in[0];
    const float* W     = (const float*)d_in[1];
    float* out         = (float*)d_out;

    const int B = in_sizes[0] / (16 * T_STEPS);  // 2048

    const size_t mask_bytes = (size_t)B * NWORDS * sizeof(unsigned long long);  // 4 MiB
    const size_t tab_bytes  = 2 * 256 * 16 * sizeof(double);                    // 64 KiB

    if (ws_size >= mask_bytes + tab_bytes) {
        unsigned long long* masks = (unsigned long long*)d_ws;
        double* tab = (double*)((char*)d_ws + mask_bytes);
        // Grid B+1: blocks 0..B-1 build masks, block B builds the byte table
        // (concurrent — no serial 1-block kernel on the critical path).
        k_maskify<<<B + 1, 256, 0, stream>>>(spike, masks, W, tab, B);
        k_scan<<<B / NB, SCAN_BLOCK, 0, stream>>>(tab, masks, out);
    } else {
        k_scan_fb<<<B / NB, SCAN_BLOCK, 0, stream>>>(W, spike, out);
    }
}

// Round 11
// 91.941 us; speedup vs baseline: 1.5898x; 1.0144x over previous
//
#include <hip/hip_runtime.h>
#include <stdint.h>

// Problem constants (B=2048, N=16, T=1024)
#define T_STEPS 1024
#define NWORDS  256          // u64 mask words per batch (4 timesteps per word)
#define NB      8            // batches per scan block
#define SCAN_BLOCK (NB * 16) // 128 threads: 8 batches x 16 output neurons

typedef float f32x4 __attribute__((ext_vector_type(4)));

// ---------------------------------------------------------------------------
// Kernel 1 (R9-proven): blocks 0..B-1: spikes -> 16-bit masks (HBM-bound
// 128 MiB read, ~21 us). Block B: build the 64 KiB f64 byte table in global
// memory, concurrent with the mask blocks. All w[] indices compile-time.
// tab[s*4096 + byte*16 + o] = (lo-nibble ordered sum)+(hi-nibble ordered sum)
// == z_{2s} + z_{2s+1} with the EXACT association tree of the absmax-0 rounds.
// ---------------------------------------------------------------------------
__global__ __launch_bounds__(256) void k_maskify(const float* __restrict__ spike,
                                                 unsigned long long* __restrict__ masks,
                                                 const float* __restrict__ W,
                                                 double* __restrict__ tab,
                                                 int B) {
    const int b  = blockIdx.x;
    const int tc = threadIdx.x;
    if (b < B) {
        const float4* sp = reinterpret_cast<const float4*>(spike) + (size_t)b * (16 * NWORDS);
        unsigned int m0 = 0, m1 = 0, m2 = 0, m3 = 0;
#pragma unroll
        for (int i = 0; i < 16; ++i) {
            float4 v = sp[i * NWORDS + tc];
            m0 |= (v.x >= 0.5f) ? (1u << i) : 0u;
            m1 |= (v.y >= 0.5f) ? (1u << i) : 0u;
            m2 |= (v.z >= 0.5f) ? (1u << i) : 0u;
            m3 |= (v.w >= 0.5f) ? (1u << i) : 0u;
        }
        masks[(size_t)b * NWORDS + tc] =
            (unsigned long long)m0 | ((unsigned long long)m1 << 16) |
            ((unsigned long long)m2 << 32) | ((unsigned long long)m3 << 48);
    } else {
        const int o = tc & 15;
        double w[16];
#pragma unroll
        for (int j = 0; j < 16; ++j) w[j] = (double)W[o * 16 + j];
#pragma unroll
        for (int k = 0; k < 32; ++k) {                 // fully unrolled
            const int e    = tc + k * 256;
            const int byte = (e >> 4) & 255;
            const int s    = k >> 4;                   // COMPILE-TIME constant
            double slo = 0.0, shi = 0.0;
#pragma unroll
            for (int j = 0; j < 4; ++j) slo += (byte & (1 << j))  ? w[8 * s + j]     : 0.0;
#pragma unroll
            for (int j = 0; j < 4; ++j) shi += (byte & (16 << j)) ? w[8 * s + 4 + j] : 0.0;
            tab[s * 4096 + byte * 16 + o] = slo + shi; // = z_{2s} + z_{2s+1}
        }
    }
}

// ---------------------------------------------------------------------------
// Kernel 2: CUBA LIF scan — asm-pipelined, all-vmcnt (R8/R9-proven ledger
// semantics), now FOUR words deep (R9's 2-word depth left ~300 cyc of L2
// gather latency on the chain).
// Body(w): GLM mask(w+6); s_waitcnt vmcnt(20); COMPUTE word w; TISSUE w+4.
// Invariant after each body's wait: newest-20 = {S(w-2), T(w+2)x8, m(w+5),
// S(w-1), T(w+3)x8, m(w+6)} -> T(w) was already forced at body w-1 (issued
// 4 bodies earlier) and mask(w+4) is forced now. COMPUTE precedes TISSUE
// into the SAME register set: the compiler's WAR dependence on the asm
// outputs pins the order. Numerics byte-identical to the absmax-0 rounds.
// ---------------------------------------------------------------------------
__global__ __launch_bounds__(SCAN_BLOCK, 1) void k_scan(const double* __restrict__ tab,
                                                        const unsigned long long* __restrict__ masks,
                                                        float* __restrict__ out) {
    const int tid = threadIdx.x;
    const int bb  = tid >> 4;
    const int o   = tid & 15;
    const int b   = blockIdx.x * NB + bb;

    const uint64_t tb     = (uint64_t)tab;
    const uint64_t mb     = (uint64_t)masks;
    const uint64_t ob_out = (uint64_t)out;
    const uint32_t ob0    = (uint32_t)(o * 8);
    const uint32_t ob1    = ob0 + 32768u;
    const uint32_t vb_m   = (uint32_t)(b * (NWORDS * 8));
    const uint32_t vb_out = (uint32_t)(b * (T_STEPS * 4));
    const int grp_sh      = tid & 48;
    const bool writer     = (o == 0);

    double c = 0.0, v = 0.0;

    // Four rotating table sets (word w lives in set w mod 4) + 6 mask regs.
    double T0_0, T0_1, T0_2, T0_3, T0_4, T0_5, T0_6, T0_7;
    double T1_0, T1_1, T1_2, T1_3, T1_4, T1_5, T1_6, T1_7;
    double T2_0, T2_1, T2_2, T2_3, T2_4, T2_5, T2_6, T2_7;
    double T3_0, T3_1, T3_2, T3_3, T3_4, T3_5, T3_6, T3_7;
    unsigned long long MA, MB, MC, MD, q0, q1;

#define GLT(DST, VOFF) \
    asm volatile("global_load_dwordx2 %0, %1, %2" : "=v"(DST) : "v"(VOFF), "s"(tb) : "memory")
#define GLM(DST, IDX) do { int _mi = (IDX); if (_mi > 255) _mi = 255;                 \
    const uint32_t _vo = vb_m + ((uint32_t)_mi << 3);                                 \
    asm volatile("global_load_dwordx2 %0, %1, %2" : "=v"(DST) : "v"(_vo), "s"(mb) : "memory"); } while (0)
#define WAITV(N) asm volatile("s_waitcnt vmcnt(" #N ")" ::: "memory")
#define SBAR __builtin_amdgcn_sched_barrier(0)

#define TISSUE(P, MW) do {                                                            \
    const uint32_t _lo = (uint32_t)(MW), _hi = (uint32_t)((MW) >> 32);                \
    uint32_t _a;                                                                      \
    _a = ob0 + ((_lo & 255u) << 7);          GLT(P##_0, _a);                          \
    _a = ob1 + (((_lo >> 8) & 255u) << 7);   GLT(P##_1, _a);                          \
    _a = ob0 + (((_lo >> 16) & 255u) << 7);  GLT(P##_2, _a);                          \
    _a = ob1 + ((_lo >> 24) << 7);           GLT(P##_3, _a);                          \
    _a = ob0 + ((_hi & 255u) << 7);          GLT(P##_4, _a);                          \
    _a = ob1 + (((_hi >> 8) & 255u) << 7);   GLT(P##_5, _a);                          \
    _a = ob0 + (((_hi >> 16) & 255u) << 7);  GLT(P##_6, _a);                          \
    _a = ob1 + ((_hi >> 24) << 7);           GLT(P##_7, _a);                          \
} while (0)

    // One recurrence step; numerics identical to the absmax-0 rounds:
    // z = (z01)+(z23) via table halves, fma(c,0.75,z), fma(v,0.97,c).
#define ZSTEP(ZL, ZH, OWEL) do {                                                      \
    const double _z = (ZL) + (ZH);                                                    \
    c = fma(c, 0.75, _z);                                                             \
    v = fma(v, 0.97, c);                                                              \
    const bool _s = (v >= 1.25);                                                      \
    const unsigned long long _bal = __ballot(_s);                                     \
    v = _s ? 0.0 : v;                                                                 \
    const uint32_t _k = __popc((uint32_t)(_bal >> grp_sh) & 0xFFFFu);                 \
    OWEL = exp2f(fmaf((float)_k, 0.62581400f, 16.0f));                                \
} while (0)

#define COMPUTE(P, WD) do {                                                           \
    f32x4 _ow;                                                                        \
    ZSTEP(P##_0, P##_1, _ow.x);                                                       \
    ZSTEP(P##_2, P##_3, _ow.y);                                                       \
    ZSTEP(P##_4, P##_5, _ow.z);                                                       \
    ZSTEP(P##_6, P##_7, _ow.w);                                                       \
    if (writer) {                                                                     \
        const uint32_t _vo = vb_out + ((uint32_t)(WD) << 4);                          \
        asm volatile("global_store_dwordx4 %0, %1, %2"                                \
                     :: "v"(_vo), "v"(_ow), "s"(ob_out) : "memory");                  \
    }                                                                                 \
} while (0)

    // Body: compute word WD from set P (already forced), then reuse P for
    // word WD+4 using mask MU (= m(WD+4), forced by this body's WAITV(20)).
#define BODY(WD, P, MU, MI) do {                                                      \
    GLM(MI, (WD) + 6);                                                                \
    WAITV(20); SBAR;                                                                  \
    COMPUTE(P, WD);                                                                   \
    TISSUE(P, MU); SBAR;                                                              \
} while (0)

    asm volatile("s_waitcnt vmcnt(0) lgkmcnt(0)" ::: "memory");

    // Prologue: 6 masks in flight; tables for words 0..3 issued.
    GLM(q0, 0); GLM(q1, 1); GLM(MA, 2); GLM(MB, 3); GLM(MC, 4); GLM(MD, 5);
    WAITV(2); SBAR;                 // m0..m3 ready; MC,MD outstanding
    TISSUE(T0, q0);
    TISSUE(T1, q1);
    TISSUE(T2, MA);
    TISSUE(T3, MB); SBAR;           // outstanding: 2 masks + 32 table loads

    // Main loop: words 0..251 (252 bodies, period-4 register rotation).
    for (int w = 0; w < 252; w += 4) {
        BODY(w,     T0, MC, MA);    // uses m(w+4)=MC,   loads m(w+6)->MA
        BODY(w + 1, T1, MD, MB);    // uses m(w+5)=MD,   loads m(w+7)->MB
        BODY(w + 2, T2, MA, MC);    // uses m(w+6)=MA,   loads m(w+8)->MC
        BODY(w + 3, T3, MB, MD);    // uses m(w+7)=MB,   loads m(w+9)->MD
    }

    // Epilogue: words 252..255 (T(252) already forced at body 251).
    COMPUTE(T0, 252);
    WAITV(21); SBAR;
    COMPUTE(T1, 253);
    WAITV(12); SBAR;
    COMPUTE(T2, 254);
    WAITV(3); SBAR;
    COMPUTE(T3, 255);
    asm volatile("s_waitcnt vmcnt(0)" ::: "memory");  // drain stores

#undef GLT
#undef GLM
#undef WAITV
#undef SBAR
#undef TISSUE
#undef ZSTEP
#undef COMPUTE
#undef BODY
}

// ---------------------------------------------------------------------------
// Fallback (only if d_ws too small — never observed): R1-style scan.
// ---------------------------------------------------------------------------
__global__ __launch_bounds__(SCAN_BLOCK) void k_scan_fb(const float* __restrict__ W,
                                                        const float* __restrict__ spike,
                                                        float* __restrict__ out) {
    __shared__ double ztab[4][16][16];
    __shared__ unsigned long long mlds[NB][NWORDS];
    __shared__ float outtab[17];
    const int tid = threadIdx.x, bb = tid >> 4, o = tid & 15;
    for (int e = tid; e < 4 * 16 * 16; e += SCAN_BLOCK) {
        const int oo = e & 15, idx = (e >> 4) & 15, seg = e >> 8;
        double s = 0.0;
#pragma unroll
        for (int j = 0; j < 4; ++j)
            if (idx & (1 << j)) s += (double)W[oo * 16 + seg * 4 + j];
        ztab[seg][idx][oo] = s;
    }
    if (tid < 17) {
        const double ln2 = 0.69314718055994530941723212145818;
        const double l2c1 = log(2.0 * cosh(1.0));
        outtab[tid] = (float)exp((16.0 - (double)tid) * ln2 + (double)tid * l2c1);
    }
    {
        const int part = tid & 15;
        const float4* spb = reinterpret_cast<const float4*>(spike) +
                            (size_t)(blockIdx.x * NB + bb) * (16 * NWORDS);
        for (int w = 0; w < 16; ++w) {
            const int tc = part * 16 + w;
            unsigned int m0 = 0, m1 = 0, m2 = 0, m3 = 0;
#pragma unroll
            for (int i = 0; i < 16; ++i) {
                float4 v = spb[i * NWORDS + tc];
                m0 |= (v.x >= 0.5f) ? (1u << i) : 0u;
                m1 |= (v.y >= 0.5f) ? (1u << i) : 0u;
                m2 |= (v.z >= 0.5f) ? (1u << i) : 0u;
                m3 |= (v.w >= 0.5f) ? (1u << i) : 0u;
            }
            mlds[bb][tc] = (unsigned long long)m0 | ((unsigned long long)m1 << 16) |
                           ((unsigned long long)m2 << 32) | ((unsigned long long)m3 << 48);
        }
    }
    __syncthreads();
    double c = 0.0, v = 0.0;
    const int b = blockIdx.x * NB + bb;
    float* outp = out + (size_t)b * T_STEPS;
    const int grp_sh = tid & 48;
    const bool writer = (o == 0);
    for (int tg = 0; tg < NWORDS; ++tg) {
        const unsigned long long mw = mlds[bb][tg];
#pragma unroll
        for (int j = 0; j < 4; ++j) {
            const unsigned int m = (unsigned int)(mw >> (16 * j)) & 0xFFFFu;
            const double z = (ztab[0][m & 15][o] + ztab[1][(m >> 4) & 15][o]) +
                             (ztab[2][(m >> 8) & 15][o] + ztab[3][(m >> 12) & 15][o]);
            c = fma(c, 0.75, z);
            v = fma(v, 0.97, c);
            const bool s = (v >= 1.25);
            const unsigned long long bal = __ballot(s);
            v = s ? 0.0 : v;
            if (writer) outp[tg * 4 + j] = outtab[(int)__popcll((bal >> grp_sh) & 0xFFFFull)];
        }
    }
}

extern "C" void kernel_launch(void* const* d_in, const int* in_sizes, int n_in,
                              void* d_out, int out_size, void* d_ws, size_t ws_size,
                              hipStream_t stream) {
    const float* spike = (const float*)d_in[0];
    const float* W     = (const float*)d_in[1];
    float* out         = (float*)d_out;

    const int B = in_sizes[0] / (16 * T_STEPS);  // 2048

    const size_t mask_bytes = (size_t)B * NWORDS * sizeof(unsigned long long);  // 4 MiB
    const size_t tab_bytes  = 2 * 256 * 16 * sizeof(double);                    // 64 KiB

    if (ws_size >= mask_bytes + tab_bytes) {
        unsigned long long* masks = (unsigned long long*)d_ws;
        double* tab = (double*)((char*)d_ws + mask_bytes);
        // Grid B+1: blocks 0..B-1 build masks, block B builds the byte table.
        k_maskify<<<B + 1, 256, 0, stream>>>(spike, masks, W, tab, B);
        k_scan<<<B / NB, SCAN_BLOCK, 0, stream>>>(tab, masks, out);
    } else {
        k_scan_fb<<<B / NB, SCAN_BLOCK, 0, stream>>>(W, spike, out);
    }
}